// Round 12
// baseline (326.755 us; speedup 1.0000x reference)
//
#include <hip/hip_runtime.h>
#include <stdint.h>

#define NNODES 100000
#define NEDGES 100000
#define DIM    256
#define NCH    4          // 2 side + 2 rel
#define ET     64         // edges per tile
#define NT     1563       // ceil(NEDGES / ET)
#define NBX    64         // blocks per channel; each block strides tiles by NBX
#define CONVB  2048       // grid-stride conversion blocks

typedef _Float16 f16x8 __attribute__((ext_vector_type(8)));
typedef _Float16 f16x4 __attribute__((ext_vector_type(4)));
typedef float f32x4  __attribute__((ext_vector_type(4)));

// ---------------------------------------------------------------------------
// Fused prep: B tables (hi/lo fp16, MFMA B-fragment order) + h f32->fp16.
// Unchanged.
// ---------------------------------------------------------------------------
__global__ void prep_fused(const float* __restrict__ RW,
                           const float* __restrict__ dside,
                           const float* __restrict__ Wrel,
                           const float* __restrict__ h,
                           _Float16* __restrict__ Bh, _Float16* __restrict__ Bl,
                           _Float16* __restrict__ H16) {
    if (blockIdx.x < 128) {
        int t = blockIdx.x * blockDim.x + threadIdx.x;   // < 32768
        int lane = t & 63;
        int ft   = (t >> 6) & 15;
        int kc   = (t >> 10) & 7;
        int c    = t >> 13;
        int quad = lane >> 4, col = lane & 15;
        int f     = ft * 16 + col;
        int kbase = kc * 32 + quad * 8;

        f16x8 vh, vl;
#pragma unroll
        for (int j = 0; j < 8; ++j) {
            int k = kbase + j;
            float val;
            if (c < 2) {
                val = dside[c * DIM + f] * RW[f * DIM + k] * dside[c * DIM + k];
            } else {
                val = Wrel[(size_t)(c - 2) * DIM * DIM + f * DIM + k];
            }
            _Float16 hi = (_Float16)val;
            vh[j] = hi;
            vl[j] = (_Float16)(val - (float)hi);
        }
        ((f16x8*)Bh)[t] = vh;
        ((f16x8*)Bl)[t] = vl;
    } else {
        const int total4 = NNODES * DIM / 4;   // 6.4e6 f32x4 chunks
        const int stride = CONVB * 256;
        int i = (blockIdx.x - 128) * 256 + (int)threadIdx.x;
        const f32x4* s4 = (const f32x4*)h;
        f16x4* d4 = (f16x4*)H16;
        for (; i + stride < total4; i += 2 * stride) {
            f32x4 a = s4[i];
            f32x4 b = s4[i + stride];
            f16x4 oa, ob;
#pragma unroll
            for (int j = 0; j < 4; ++j) { oa[j] = (_Float16)a[j]; ob[j] = (_Float16)b[j]; }
            d4[i] = oa; d4[i + stride] = ob;
        }
        if (i < total4) {
            f32x4 a = s4[i];
            f16x4 o;
#pragma unroll
            for (int j = 0; j < 4; ++j) o[j] = (_Float16)a[j];
            d4[i] = o;
        }
    }
}

// 16-lane-row sum reduction on the VALU via DPP (confirmed round-7 win).
__device__ __forceinline__ float dpp_reduce16(float s) {
    union { float f; int i; } u, v;
    u.f = s; v.i = __builtin_amdgcn_update_dpp(0, u.i, 0xB1,  0xF, 0xF, true); s += v.f;
    u.f = s; v.i = __builtin_amdgcn_update_dpp(0, u.i, 0x4E,  0xF, 0xF, true); s += v.f;
    u.f = s; v.i = __builtin_amdgcn_update_dpp(0, u.i, 0x141, 0xF, 0xF, true); s += v.f;
    u.f = s; v.i = __builtin_amdgcn_update_dpp(0, u.i, 0x140, 0xF, 0xF, true); s += v.f;
    return s;
}

// ---------------------------------------------------------------------------
// Edge kernel v11 = v10's structure with CONVENTIONAL staging (no
// global_load_lds — v10 failed 4 container attempts; every construct here
// has benched cleanly in rounds 6-9, so a 5th failure = infra, proven).
//  - LDS double-buffer, XOR-swizzled linear rows:
//      phys 16B-slot p of row r holds logical slot p^(r&7).
//    Write side applies the swizzle on the GLOBAL LOAD source offset; read
//    side applies it on the LDS address (same involution both sides).
//    Stage ds_write_b128s are contiguous -> conflict-free by construction.
//  - T14 split: global loads for tile t+1 issue right after BARRIER1
//    (in flight under the whole K-loop); ds_writes land after the K-loop
//    into buf[par^1]. In v7 these writes sat in the serial window between
//    barrier2(t-1) and barrier1(t). rA/rV live only WITHIN one body call
//    (v7's pA/pV lived across barriers) -> less cross-barrier pressure.
//  - s_setprio(1) around the MFMA cluster (T5: structure now has wave
//    role-split: stage/epilogue waves vs K-loop waves).
//  Epilogue (DPP + red + plain store) identical to v7 (proven 120.5us).
// ---------------------------------------------------------------------------
__global__ __launch_bounds__(512, 1)
void edge_kernel(const _Float16* __restrict__ H16,
                 const int* __restrict__ src_idx,
                 const int* __restrict__ dst_idx,
                 const float* __restrict__ brel,
                 const _Float16* __restrict__ Bh_sw,
                 const _Float16* __restrict__ Bl_sw,
                 float* __restrict__ out) {
    const int c    = blockIdx.y;
    const int tid  = threadIdx.x;
    const int w    = tid >> 6;          // 0..7
    const int lane = tid & 63;
    const int quad = lane >> 4, col = lane & 15;
    const int c7   = col & 7;

    __shared__ __align__(16) _Float16 s_a[2][ET * DIM];   // 32 KB each
    __shared__ __align__(16) _Float16 s_v[2][ET * DIM];   // total 128 KB
    __shared__ float red[8][ET];                          // 2 KB

    // ---- B registers: wave w holds ft = {2w, 2w+1}, all kc, hi+lo ----
    f16x8 Bh_r[8][2], Bl_r[8][2];
    {
        const f16x8* bh = (const f16x8*)Bh_sw;
        const f16x8* bl = (const f16x8*)Bl_sw;
#pragma unroll
        for (int kc = 0; kc < 8; ++kc)
#pragma unroll
            for (int ftl = 0; ftl < 2; ++ftl) {
                int o = ((c * 8 + kc) * 16 + (w * 2 + ftl)) * 64 + lane;
                Bh_r[kc][ftl] = bh[o];
                Bl_r[kc][ftl] = bl[o];
            }
    }
#pragma unroll
    for (int kc = 0; kc < 8; ++kc)
#pragma unroll
        for (int ftl = 0; ftl < 2; ++ftl)
            asm volatile("" : "+v"(Bh_r[kc][ftl]), "+v"(Bl_r[kc][ftl]));

    float bias[2];
#pragma unroll
    for (int ftl = 0; ftl < 2; ++ftl) {
        int f = (w * 2 + ftl) * 16 + col;
        bias[ftl] = (c >= 2) ? brel[(size_t)(c - 2) * DIM + f] : 0.f;
    }

    // Lane-packed index loads: lanes 0..7 -> src idx of rows w*8+0..7,
    // lanes 8..15 -> dst idx.
    const int  j8   = lane & 7;
    const bool isV  = (lane & 8) != 0;
    const int* ibase = (isV ? dst_idx : src_idx) + (size_t)c * NEDGES;

    auto loadpack = [&](int t) -> int {
        int e = t * ET + w * 8 + j8;
        if (e >= NEDGES) e = NEDGES - 1;
        return ibase[e];
    };

    // Per-lane staging geometry: iteration i covers rows {2i, 2i+1} of this
    // wave's 8 rows; lane handles row r = 2i + (lane>>5), phys 16B-slot
    // p = lane&31, fetching LOGICAL slot p^(r&7) (pre-swizzled source).
    const int halfsel = lane >> 5;            // 0: rows 2i, 1: rows 2i+1
    const int p31     = lane & 31;

    f16x8 rA[4], rV[4];
    auto loadTileRegs = [&](int ip) {
#pragma unroll
        for (int i = 0; i < 4; ++i) {
            int a0 = __builtin_amdgcn_readlane(ip, 2 * i);
            int a1 = __builtin_amdgcn_readlane(ip, 2 * i + 1);
            int v0 = __builtin_amdgcn_readlane(ip, 8 + 2 * i);
            int v1 = __builtin_amdgcn_readlane(ip, 8 + 2 * i + 1);
            int idxA = halfsel ? a1 : a0;
            int idxV = halfsel ? v1 : v0;
            int r7  = (2 * i + halfsel) & 7;
            int lsl = (p31 ^ r7) << 3;        // logical f16 offset in row
            rA[i] = *(const f16x8*)(H16 + (size_t)idxA * DIM + lsl);
            rV[i] = *(const f16x8*)(H16 + (size_t)idxV * DIM + lsl);
        }
    };
    auto writeTileRegs = [&](_Float16* sa, _Float16* sv) {
#pragma unroll
        for (int i = 0; i < 4; ++i) {
            int dst = (w * 8 + 2 * i + halfsel) * DIM + p31 * 8;  // linear phys
            *(f16x8*)&sa[dst] = rA[i];
            *(f16x8*)&sv[dst] = rV[i];
        }
    };

    // ---- Prologue: stage tile t0 into buf 0; preload idx for t0+NBX ----
    const int t0 = blockIdx.x;
    loadTileRegs(loadpack(t0));
    writeTileRegs(s_a[0], s_v[0]);
    int ipk0 = 0, ipk1 = 0;
    if (t0 + NBX < NT) ipk1 = loadpack(t0 + NBX);

    // ---- Tile body ----
    auto body = [&](int t, int par, int& ipkUse, int& ipkLoad) {
        _Float16* sa = s_a[par];
        _Float16* sv = s_v[par];

        __syncthreads();   // BARRIER1: buf[par] fully staged; red free

        // T14 issue-early: loads for tile t+NBX fly under the K-loop
        if (t + 2 * NBX < NT) ipkLoad = loadpack(t + 2 * NBX);
        const bool havenext = (t + NBX < NT);
        if (havenext) loadTileRegs(ipkUse);

        // K-loop: A from LDS (swizzled read addr), B from registers
        f32x4 acc[4][2];
#pragma unroll
        for (int mt = 0; mt < 4; ++mt)
#pragma unroll
            for (int ftl = 0; ftl < 2; ++ftl) acc[mt][ftl] = (f32x4){0.f, 0.f, 0.f, 0.f};

        __builtin_amdgcn_s_setprio(1);
#pragma unroll
        for (int kc = 0; kc < 8; ++kc) {
            f16x8 A[4];
#pragma unroll
            for (int mt = 0; mt < 4; ++mt)
                A[mt] = *(const f16x8*)&sa[(mt * 16 + col) * DIM + (((kc * 4 + quad) ^ c7) << 3)];
#pragma unroll
            for (int ftl = 0; ftl < 2; ++ftl) {
#pragma unroll
                for (int mt = 0; mt < 4; ++mt)
                    acc[mt][ftl] = __builtin_amdgcn_mfma_f32_16x16x32_f16(A[mt], Bh_r[kc][ftl], acc[mt][ftl], 0, 0, 0);
#pragma unroll
                for (int mt = 0; mt < 4; ++mt)
                    acc[mt][ftl] = __builtin_amdgcn_mfma_f32_16x16x32_f16(A[mt], Bl_r[kc][ftl], acc[mt][ftl], 0, 0, 0);
            }
        }
        __builtin_amdgcn_s_setprio(0);

        // Write-late: stage tile t+NBX into the OTHER buffer (vmcnt wait
        // lands here, hidden by the K-loop above). Safe vs iter t-1 readers
        // of buf[par^1]: ordered by BARRIER1 of this iter.
        if (havenext) writeTileRegs(s_a[par ^ 1], s_v[par ^ 1]);

        // Epilogue: score_e = sum_f (C[e][f] + bias[f]) * V[e][f]
        float psum[4][4];
#pragma unroll
        for (int mt = 0; mt < 4; ++mt) {
#pragma unroll
            for (int r = 0; r < 4; ++r) {
                int el = mt * 16 + quad * 4 + r;
                float s = 0.f;
#pragma unroll
                for (int ftl = 0; ftl < 2; ++ftl) {
                    int f = (w * 2 + ftl) * 16 + col;
                    int phys = (f >> 3) ^ (el & 7);
                    float v = (float)sv[el * DIM + phys * 8 + (f & 7)];
                    s += (acc[mt][ftl][r] + bias[ftl]) * v;
                }
                psum[mt][r] = dpp_reduce16(s);
            }
        }
        if (col == 0) {
#pragma unroll
            for (int mt = 0; mt < 4; ++mt)
#pragma unroll
                for (int r = 0; r < 4; ++r)
                    red[w][mt * 16 + quad * 4 + r] = psum[mt][r];
        }
        __syncthreads();   // BARRIER2: red ready

        if (tid < ET) {
            int e = t * ET + tid;
            if (e < NEDGES) {
                float s = 0.f;
#pragma unroll
                for (int i = 0; i < 8; ++i) s += red[i][tid];
                out[(size_t)c * NEDGES + e] = s;
            }
        }
        // red write-after-read across tiles ordered by next BARRIER1.
    };

    int t = t0;
    while (true) {
        body(t, 0, ipk1, ipk0);            // parity 0
        t += NBX; if (t >= NT) break;
        body(t, 1, ipk0, ipk1);            // parity 1
        t += NBX; if (t >= NT) break;
    }
}

extern "C" void kernel_launch(void* const* d_in, const int* in_sizes, int n_in,
                              void* d_out, int out_size, void* d_ws, size_t ws_size,
                              hipStream_t stream) {
    const float* hmat  = (const float*)d_in[0];
    const int*   src   = (const int*)d_in[1];
    const int*   dst   = (const int*)d_in[2];
    const float* RW    = (const float*)d_in[3];
    const float* dside = (const float*)d_in[4];
    const float* Wrel  = (const float*)d_in[5];
    const float* brel  = (const float*)d_in[6];
    float* out = (float*)d_out;

    // Workspace: Bh (512 KB) | Bl (512 KB) | H16 (51.2 MB)
    const size_t nB = (size_t)NCH * DIM * DIM;   // fp16 per table
    _Float16* Bh  = (_Float16*)d_ws;
    _Float16* Bl  = Bh + nB;
    _Float16* H16 = Bl + nB;

    prep_fused<<<dim3(128 + CONVB), dim3(256), 0, stream>>>(
        RW, dside, Wrel, hmat, Bh, Bl, H16);

    dim3 grid(NBX, NCH);
    edge_kernel<<<grid, dim3(512), 0, stream>>>(H16, src, dst, brel, Bh, Bl, out);
}

// Round 13
// 270.999 us; speedup vs baseline: 1.2057x; 1.2057x over previous
//
#include <hip/hip_runtime.h>
#include <stdint.h>

#define NNODES 100000
#define NEDGES 100000
#define DIM    256
#define NCH    4          // 2 side + 2 rel
#define ET     64         // edges per tile
#define NT     1563       // ceil(NEDGES / ET)
#define NBX    64         // blocks per channel; each block strides tiles by NBX
#define RSF    264        // fp16 per staged row (256 + 8 pad -> conflict-benign)
#define CONVB  2048       // grid-stride conversion blocks

typedef _Float16 f16x8 __attribute__((ext_vector_type(8)));
typedef _Float16 f16x4 __attribute__((ext_vector_type(4)));
typedef float f32x4  __attribute__((ext_vector_type(4)));

// ---------------------------------------------------------------------------
// Fused prep: B tables (hi/lo fp16, MFMA B-fragment order) + h f32->fp16.
// Unchanged.
// ---------------------------------------------------------------------------
__global__ void prep_fused(const float* __restrict__ RW,
                           const float* __restrict__ dside,
                           const float* __restrict__ Wrel,
                           const float* __restrict__ h,
                           _Float16* __restrict__ Bh, _Float16* __restrict__ Bl,
                           _Float16* __restrict__ H16) {
    if (blockIdx.x < 128) {
        int t = blockIdx.x * blockDim.x + threadIdx.x;   // < 32768
        int lane = t & 63;
        int ft   = (t >> 6) & 15;
        int kc   = (t >> 10) & 7;
        int c    = t >> 13;
        int quad = lane >> 4, col = lane & 15;
        int f     = ft * 16 + col;
        int kbase = kc * 32 + quad * 8;

        f16x8 vh, vl;
#pragma unroll
        for (int j = 0; j < 8; ++j) {
            int k = kbase + j;
            float val;
            if (c < 2) {
                val = dside[c * DIM + f] * RW[f * DIM + k] * dside[c * DIM + k];
            } else {
                val = Wrel[(size_t)(c - 2) * DIM * DIM + f * DIM + k];
            }
            _Float16 hi = (_Float16)val;
            vh[j] = hi;
            vl[j] = (_Float16)(val - (float)hi);
        }
        ((f16x8*)Bh)[t] = vh;
        ((f16x8*)Bl)[t] = vl;
    } else {
        const int total4 = NNODES * DIM / 4;   // 6.4e6 f32x4 chunks
        const int stride = CONVB * 256;
        int i = (blockIdx.x - 128) * 256 + (int)threadIdx.x;
        const f32x4* s4 = (const f32x4*)h;
        f16x4* d4 = (f16x4*)H16;
        for (; i + stride < total4; i += 2 * stride) {
            f32x4 a = s4[i];
            f32x4 b = s4[i + stride];
            f16x4 oa, ob;
#pragma unroll
            for (int j = 0; j < 4; ++j) { oa[j] = (_Float16)a[j]; ob[j] = (_Float16)b[j]; }
            d4[i] = oa; d4[i + stride] = ob;
        }
        if (i < total4) {
            f32x4 a = s4[i];
            f16x4 o;
#pragma unroll
            for (int j = 0; j < 4; ++j) o[j] = (_Float16)a[j];
            d4[i] = o;
        }
    }
}

// 16-lane-row sum reduction on the VALU via DPP (confirmed round-7 win).
__device__ __forceinline__ float dpp_reduce16(float s) {
    union { float f; int i; } u, v;
    u.f = s; v.i = __builtin_amdgcn_update_dpp(0, u.i, 0xB1,  0xF, 0xF, true); s += v.f;
    u.f = s; v.i = __builtin_amdgcn_update_dpp(0, u.i, 0x4E,  0xF, 0xF, true); s += v.f;
    u.f = s; v.i = __builtin_amdgcn_update_dpp(0, u.i, 0x141, 0xF, 0xF, true); s += v.f;
    u.f = s; v.i = __builtin_amdgcn_update_dpp(0, u.i, 0x140, 0xF, 0xF, true); s += v.f;
    return s;
}

// ---------------------------------------------------------------------------
// Edge kernel v12 = v7 (proven 120.5us) with ONE change: the next-tile
// gather block moves from BEFORE BARRIER1 to AFTER it.
//  ROUND-12 LESSON (3rd spill confirmation): 128 AGPR (B) + 128 VGPR is
//  exactly full; only v7's register schedule fits. So no new live state.
//  THE DRAIN THEORY: hipcc emits s_waitcnt vmcnt(0) before every
//  s_barrier. In v7 the 16 scattered gathers were issued ~100cy before
//  BARRIER1 -> each tile ate ~500-900cy of exposed L3/HBM latency at the
//  barrier. Issuing them right AFTER BARRIER1 moves their drain point to
//  BARRIER2, giving K-loop+epilogue (~3-4Kcy) of cover. pA/pV liveness
//  SHRINKS (spans 1 barrier instead of 2) -> spill risk strictly lower.
// ---------------------------------------------------------------------------
__global__ __launch_bounds__(512, 1)
void edge_kernel(const _Float16* __restrict__ H16,
                 const int* __restrict__ src_idx,
                 const int* __restrict__ dst_idx,
                 const float* __restrict__ brel,
                 const _Float16* __restrict__ Bh_sw,
                 const _Float16* __restrict__ Bl_sw,
                 float* __restrict__ out) {
    const int c    = blockIdx.y;
    const int tid  = threadIdx.x;
    const int w    = tid >> 6;          // 0..7
    const int lane = tid & 63;
    const int quad = lane >> 4, col = lane & 15;

    __shared__ __align__(16) _Float16 s_a[ET * RSF];   // 33,792 B
    __shared__ __align__(16) _Float16 s_v[ET * RSF];   // 33,792 B
    __shared__ float red[8][ET];                       // 2 KB

    // ---- B registers: wave w holds ft = {2w, 2w+1}, all kc, hi+lo ----
    f16x8 Bh_r[8][2], Bl_r[8][2];
    {
        const f16x8* bh = (const f16x8*)Bh_sw;
        const f16x8* bl = (const f16x8*)Bl_sw;
#pragma unroll
        for (int kc = 0; kc < 8; ++kc)
#pragma unroll
            for (int ftl = 0; ftl < 2; ++ftl) {
                int o = ((c * 8 + kc) * 16 + (w * 2 + ftl)) * 64 + lane;
                Bh_r[kc][ftl] = bh[o];
                Bl_r[kc][ftl] = bl[o];
            }
    }
    // Pin B (kept from v6; B lives in AGPRs either way).
#pragma unroll
    for (int kc = 0; kc < 8; ++kc)
#pragma unroll
        for (int ftl = 0; ftl < 2; ++ftl)
            asm volatile("" : "+v"(Bh_r[kc][ftl]), "+v"(Bl_r[kc][ftl]));

    float bias[2];
#pragma unroll
    for (int ftl = 0; ftl < 2; ++ftl) {
        int f = (w * 2 + ftl) * 16 + col;
        bias[ftl] = (c >= 2) ? brel[(size_t)(c - 2) * DIM + f] : 0.f;
    }

    // Lane-packed index loads: lanes 0..7 -> src idx of rows w*8+0..7,
    // lanes 8..15 -> dst idx (pattern repeats harmlessly for lanes >= 16).
    const int  j8   = lane & 7;
    const bool isV  = (lane & 8) != 0;
    const int* ibase = (isV ? dst_idx : src_idx) + (size_t)c * NEDGES;

    auto loadpack = [&](int t) -> int {
        int e = t * ET + w * 8 + j8;
        if (e >= NEDGES) e = NEDGES - 1;
        return ibase[e];
    };

    // ---- Prologue: gather tile t0 rows; preload idx pack for t0+NBX ----
    const int t0 = blockIdx.x;
    f16x4 pA[8], pV[8];
    {
        int ip = loadpack(t0);
#pragma unroll
        for (int i = 0; i < 8; ++i) {
            int ia = __shfl(ip, i, 64);
            int iv = __shfl(ip, 8 + i, 64);
            pA[i] = *(const f16x4*)(H16 + (size_t)ia * DIM + lane * 4);
            pV[i] = *(const f16x4*)(H16 + (size_t)iv * DIM + lane * 4);
        }
    }
    int ipk0 = 0, ipk1 = 0;
    if (t0 + NBX < NT) ipk1 = loadpack(t0 + NBX);

    // ---- Tile body (ipkUse = idx for t+NBX, ipkLoad gets t+2*NBX) ----
    auto body = [&](int t, int& ipkUse, int& ipkLoad) {
        // stage tile t rows (gathered during previous tile)
#pragma unroll
        for (int i = 0; i < 8; ++i) {
            int lr = w * 8 + i;
            *(f16x4*)&s_a[lr * RSF + lane * 4] = pA[i];
            *(f16x4*)&s_v[lr * RSF + lane * 4] = pV[i];
        }

        __syncthreads();   // BARRIER1 (drains only the ds_writes above)

        // Issue idx loads 2 tiles ahead + row gathers 1 tile ahead NOW:
        // their drain point is BARRIER2, covered by K-loop + epilogue.
        if (t + 2 * NBX < NT) ipkLoad = loadpack(t + 2 * NBX);
        if (t + NBX < NT) {
#pragma unroll
            for (int i = 0; i < 8; ++i) {
                int ia = __shfl(ipkUse, i, 64);
                int iv = __shfl(ipkUse, 8 + i, 64);
                pA[i] = *(const f16x4*)(H16 + (size_t)ia * DIM + lane * 4);
                pV[i] = *(const f16x4*)(H16 + (size_t)iv * DIM + lane * 4);
            }
        }

        // K-loop: A from LDS, B from registers (AGPR-resident), 2-term MFMA
        f32x4 acc[4][2];
#pragma unroll
        for (int mt = 0; mt < 4; ++mt)
#pragma unroll
            for (int ftl = 0; ftl < 2; ++ftl) acc[mt][ftl] = (f32x4){0.f, 0.f, 0.f, 0.f};

#pragma unroll
        for (int kc = 0; kc < 8; ++kc) {
            f16x8 A[4];
#pragma unroll
            for (int mt = 0; mt < 4; ++mt)
                A[mt] = *(const f16x8*)&s_a[(mt * 16 + col) * RSF + kc * 32 + quad * 8];
#pragma unroll
            for (int ftl = 0; ftl < 2; ++ftl) {
#pragma unroll
                for (int mt = 0; mt < 4; ++mt)
                    acc[mt][ftl] = __builtin_amdgcn_mfma_f32_16x16x32_f16(A[mt], Bh_r[kc][ftl], acc[mt][ftl], 0, 0, 0);
#pragma unroll
                for (int mt = 0; mt < 4; ++mt)
                    acc[mt][ftl] = __builtin_amdgcn_mfma_f32_16x16x32_f16(A[mt], Bl_r[kc][ftl], acc[mt][ftl], 0, 0, 0);
            }
        }

        // Epilogue: score_e = sum_f (C[e][f] + bias[f]) * V[e][f];
        // DPP reduction on the VALU (round-7 win), private red slots.
#pragma unroll
        for (int mt = 0; mt < 4; ++mt) {
            float ps[4];
#pragma unroll
            for (int r = 0; r < 4; ++r) {
                int el = mt * 16 + quad * 4 + r;
                float s = 0.f;
#pragma unroll
                for (int ftl = 0; ftl < 2; ++ftl) {
                    int f = (w * 2 + ftl) * 16 + col;
                    float v = (float)s_v[el * RSF + f];
                    s += (acc[mt][ftl][r] + bias[ftl]) * v;
                }
                ps[r] = dpp_reduce16(s);
            }
            if (col == 0) {
#pragma unroll
                for (int r = 0; r < 4; ++r)
                    red[w][mt * 16 + quad * 4 + r] = ps[r];
            }
        }

        __syncthreads();   // BARRIER2: red ready (gathers drain here, covered)

        if (tid < ET) {
            int e = t * ET + tid;
            if (e < NEDGES) {
                float s = 0.f;
#pragma unroll
                for (int i = 0; i < 8; ++i) s += red[i][tid];
                out[(size_t)c * NEDGES + e] = s;
            }
        }
        // red write-after-read across tiles ordered by next BARRIER1.
    };

    int t = t0;
    while (true) {
        body(t, ipk1, ipk0);            // parity 0: use t+NBX idx from ipk1
        t += NBX; if (t >= NT) break;
        body(t, ipk0, ipk1);            // parity 1
        t += NBX; if (t >= NT) break;
    }
}

extern "C" void kernel_launch(void* const* d_in, const int* in_sizes, int n_in,
                              void* d_out, int out_size, void* d_ws, size_t ws_size,
                              hipStream_t stream) {
    const float* hmat  = (const float*)d_in[0];
    const int*   src   = (const int*)d_in[1];
    const int*   dst   = (const int*)d_in[2];
    const float* RW    = (const float*)d_in[3];
    const float* dside = (const float*)d_in[4];
    const float* Wrel  = (const float*)d_in[5];
    const float* brel  = (const float*)d_in[6];
    float* out = (float*)d_out;

    // Workspace: Bh (512 KB) | Bl (512 KB) | H16 (51.2 MB)
    const size_t nB = (size_t)NCH * DIM * DIM;   // fp16 per table
    _Float16* Bh  = (_Float16*)d_ws;
    _Float16* Bl  = Bh + nB;
    _Float16* H16 = Bl + nB;

    prep_fused<<<dim3(128 + CONVB), dim3(256), 0, stream>>>(
        RW, dside, Wrel, hmat, Bh, Bl, H16);

    dim3 grid(NBX, NCH);
    edge_kernel<<<grid, dim3(512), 0, stream>>>(H16, src, dst, brel, Bh, Bl, out);
}